// Round 3
// baseline (178.139 us; speedup 1.0000x reference)
//
#include <hip/hip_runtime.h>
#include <math.h>

#define DIM 64
#define NNB 16
#define BATCH 16384

typedef float4 f4;

__device__ __forceinline__ float dot4(const f4 a, const f4 b) {
    return fmaf(a.x, b.x, fmaf(a.y, b.y, fmaf(a.z, b.z, a.w * b.w)));
}

// Sum across the 4 lane-groups (lanes differing in bits 4,5); chunk stays put.
__device__ __forceinline__ f4 xgrp_sum(f4 v) {
    v.x += __shfl_xor(v.x, 16, 64); v.y += __shfl_xor(v.y, 16, 64);
    v.z += __shfl_xor(v.z, 16, 64); v.w += __shfl_xor(v.w, 16, 64);
    v.x += __shfl_xor(v.x, 32, 64); v.y += __shfl_xor(v.y, 32, 64);
    v.z += __shfl_xor(v.z, 32, 64); v.w += __shfl_xor(v.w, 32, 64);
    return v;
}

template <int WPB>
__global__ __launch_bounds__(WPB * 64, 4) void klgcn_kernel(
    const int* __restrict__ u, const int* __restrict__ v,
    const int* __restrict__ user_neighbor, const int* __restrict__ item_neighbor,
    const int* __restrict__ adj_ent, const int* __restrict__ adj_rel,
    const float* __restrict__ usr_emb, const float* __restrict__ ent_emb,
    const float* __restrict__ rel_emb, const float* __restrict__ agg_W,
    const float* __restrict__ agg_b, float* __restrict__ out)
{
    const int wave = threadIdx.x >> 6;
    const int lane = threadIdx.x & 63;
    const int g = lane >> 4;   // group 0..3: which of 4 rows per gather instr
    const int s = lane & 15;   // chunk 0..15: dims [4s, 4s+4)
    const int b = __builtin_amdgcn_readfirstlane(blockIdx.x * WPB + wave);

    const f4* __restrict__ usr4 = (const f4*)usr_emb;
    const f4* __restrict__ ent4 = (const f4*)ent_emb;
    const f4* __restrict__ rel4 = (const f4*)rel_emb;
    const f4* __restrict__ W4   = (const f4*)agg_W;
    const f4* __restrict__ b4p  = (const f4*)agg_b;

    const int ub = __builtin_amdgcn_readfirstlane(u[b]);
    const int vb = __builtin_amdgcn_readfirstlane(v[b]);

    // Wave-uniform indices -> scalar regs / SMEM path.
    int i_it[NNB], i_un[NNB], i_ar[NNB], i_ae[NNB];
#pragma unroll
    for (int n = 0; n < NNB; n++)
        i_it[n] = __builtin_amdgcn_readfirstlane(item_neighbor[b * NNB + n]);
#pragma unroll
    for (int n = 0; n < NNB; n++)
        i_un[n] = __builtin_amdgcn_readfirstlane(user_neighbor[b * NNB + n]);
#pragma unroll
    for (int n = 0; n < NNB; n++)
        i_ar[n] = __builtin_amdgcn_readfirstlane(adj_rel[vb * NNB + n]);
#pragma unroll
    for (int n = 0; n < NNB; n++)
        i_ae[n] = __builtin_amdgcn_readfirstlane(adj_ent[vb * NNB + n]);

    // ---- Issue all gathers: each instruction fetches 4 rows (1 KB/wave).
    // Group g takes neighbor rows {4k+g}.
    f4 ue4 = usr4[(long)ub * 16 + s];
    f4 ie4 = ent4[(long)vb * 16 + s];
    f4 Re[4], Ag[4], Lu[4], Li[4];
#pragma unroll
    for (int k = 0; k < 4; k++) Re[k] = rel4[i_ar[4 * k + g] * 16 + s];
#pragma unroll
    for (int k = 0; k < 4; k++) Ag[k] = ent4[(long)i_ae[4 * k + g] * 16 + s];
#pragma unroll
    for (int k = 0; k < 4; k++) Lu[k] = usr4[(long)i_it[4 * k + g] * 16 + s];
#pragma unroll
    for (int k = 0; k < 4; k++) Li[k] = ent4[(long)i_un[4 * k + g] * 16 + s];

    // ---- Attention scores: sc[k] = dot(ue, rel_row[4k+g]) (in-group reduce).
    float sc[4];
#pragma unroll
    for (int k = 0; k < 4; k++) {
        float p = dot4(ue4, Re[k]);
        p += __shfl_xor(p, 1, 64); p += __shfl_xor(p, 2, 64);
        p += __shfl_xor(p, 4, 64); p += __shfl_xor(p, 8, 64);
        sc[k] = p;  // identical across the 16 lanes of group g
    }
    float m = fmaxf(fmaxf(sc[0], sc[1]), fmaxf(sc[2], sc[3]));
    m = fmaxf(m, __shfl_xor(m, 16, 64));
    m = fmaxf(m, __shfl_xor(m, 32, 64));
    float e[4];
    float ssum = 0.f;
#pragma unroll
    for (int k = 0; k < 4; k++) { e[k] = __expf(sc[k] - m); ssum += e[k]; }
    ssum += __shfl_xor(ssum, 16, 64);
    ssum += __shfl_xor(ssum, 32, 64);
    const float inv = 1.0f / ssum;

    // ---- neighbors_agg: this lane holds exactly the attn weights for rows 4k+g.
    f4 ag = {0.f, 0.f, 0.f, 0.f};
#pragma unroll
    for (int k = 0; k < 4; k++) {
        ag.x = fmaf(e[k], Ag[k].x, ag.x);
        ag.y = fmaf(e[k], Ag[k].y, ag.y);
        ag.z = fmaf(e[k], Ag[k].z, ag.z);
        ag.w = fmaf(e[k], Ag[k].w, ag.w);
    }
    ag = xgrp_sum(ag);

    f4 comb;
    comb.x = fmaf(ag.x, inv, ie4.x);
    comb.y = fmaf(ag.y, inv, ie4.y);
    comb.z = fmaf(ag.z, inv, ie4.z);
    comb.w = fmaf(ag.w, inv, ie4.w);
    const float cc[4] = {comb.x, comb.y, comb.z, comb.w};

    // ---- lite sums (consume after scores so score-loads wait first).
    f4 lu;
    lu.x = Lu[0].x + Lu[1].x + Lu[2].x + Lu[3].x;
    lu.y = Lu[0].y + Lu[1].y + Lu[2].y + Lu[3].y;
    lu.z = Lu[0].z + Lu[1].z + Lu[2].z + Lu[3].z;
    lu.w = Lu[0].w + Lu[1].w + Lu[2].w + Lu[3].w;
    lu = xgrp_sum(lu);
    f4 li;
    li.x = Li[0].x + Li[1].x + Li[2].x + Li[3].x;
    li.y = Li[0].y + Li[1].y + Li[2].y + Li[3].y;
    li.z = Li[0].z + Li[1].z + Li[2].z + Li[3].z;
    li.w = Li[0].w + Li[1].w + Li[2].w + Li[3].w;
    li = xgrp_sum(li);

    // ---- 64x64 matvec: lane (g,s) accumulates d in [16g,16g+16) for out-chunk s.
    // combined[d] broadcast: chunk d>>2 = 4g+(j>>2) lives in lane 20g+(j>>2) of
    // this lane's own group (comb replicated across groups after xgrp_sum).
    f4 acc = {0.f, 0.f, 0.f, 0.f};
#pragma unroll
    for (int j = 0; j < 16; j++) {
        const int d = 16 * g + j;
        const float cd = __shfl(cc[j & 3], 20 * g + (j >> 2), 64);
        const f4 w = W4[d * 16 + s];
        acc.x = fmaf(cd, w.x, acc.x);
        acc.y = fmaf(cd, w.y, acc.y);
        acc.z = fmaf(cd, w.z, acc.z);
        acc.w = fmaf(cd, w.w, acc.w);
    }
    acc = xgrp_sum(acc);
    const f4 bias = b4p[s];
    f4 item4;
    item4.x = tanhf(acc.x + bias.x);
    item4.y = tanhf(acc.y + bias.y);
    item4.z = tanhf(acc.z + bias.z);
    item4.w = tanhf(acc.w + bias.w);

    // ---- final score: dot over 64 dims = in-group reduce over 16 chunks.
    f4 uf, itf;
    uf.x = 0.5f * fmaf(lu.x, 1.f / NNB, ue4.x);
    uf.y = 0.5f * fmaf(lu.y, 1.f / NNB, ue4.y);
    uf.z = 0.5f * fmaf(lu.z, 1.f / NNB, ue4.z);
    uf.w = 0.5f * fmaf(lu.w, 1.f / NNB, ue4.w);
    itf.x = 0.5f * fmaf(li.x, 1.f / NNB, item4.x);
    itf.y = 0.5f * fmaf(li.y, 1.f / NNB, item4.y);
    itf.z = 0.5f * fmaf(li.z, 1.f / NNB, item4.z);
    itf.w = 0.5f * fmaf(li.w, 1.f / NNB, item4.w);

    float p = dot4(uf, itf);
    p += __shfl_xor(p, 1, 64); p += __shfl_xor(p, 2, 64);
    p += __shfl_xor(p, 4, 64); p += __shfl_xor(p, 8, 64);

    if (lane == 0) out[b] = 1.0f / (1.0f + __expf(-p));
}

extern "C" void kernel_launch(void* const* d_in, const int* in_sizes, int n_in,
                              void* d_out, int out_size, void* d_ws, size_t ws_size,
                              hipStream_t stream)
{
    const int*   u             = (const int*)d_in[0];
    const int*   v             = (const int*)d_in[1];
    const int*   user_neighbor = (const int*)d_in[2];
    const int*   item_neighbor = (const int*)d_in[3];
    const int*   adj_ent       = (const int*)d_in[4];
    const int*   adj_rel       = (const int*)d_in[5];
    const float* usr_emb       = (const float*)d_in[6];
    const float* ent_emb       = (const float*)d_in[7];
    const float* rel_emb       = (const float*)d_in[8];
    const float* agg_W         = (const float*)d_in[9];
    const float* agg_b         = (const float*)d_in[10];
    float* out = (float*)d_out;

    constexpr int WPB = 4;  // 4 waves/block, one batch element per wave
    dim3 grid(BATCH / WPB), block(WPB * 64);
    klgcn_kernel<WPB><<<grid, block, 0, stream>>>(
        u, v, user_neighbor, item_neighbor, adj_ent, adj_rel,
        usr_emb, ent_emb, rel_emb, agg_W, agg_b, out);
}

// Round 4
// 154.673 us; speedup vs baseline: 1.1517x; 1.1517x over previous
//
#include <hip/hip_runtime.h>
#include <math.h>

#define DIM 64
#define NNB 16
#define BATCH 16384

typedef float4 f4;

__device__ __forceinline__ float dot4(const f4 a, const f4 b) {
    return fmaf(a.x, b.x, fmaf(a.y, b.y, fmaf(a.z, b.z, a.w * b.w)));
}

// Sum across the 4 lane-groups (lanes differing in bits 4,5); chunk stays put.
__device__ __forceinline__ f4 xgrp_sum(f4 v) {
    v.x += __shfl_xor(v.x, 16, 64); v.y += __shfl_xor(v.y, 16, 64);
    v.z += __shfl_xor(v.z, 16, 64); v.w += __shfl_xor(v.w, 16, 64);
    v.x += __shfl_xor(v.x, 32, 64); v.y += __shfl_xor(v.y, 32, 64);
    v.z += __shfl_xor(v.z, 32, 64); v.w += __shfl_xor(v.w, 32, 64);
    return v;
}

template <int WPB>
__global__ __launch_bounds__(WPB * 64, 4) void klgcn_kernel(
    const int* __restrict__ u, const int* __restrict__ v,
    const int* __restrict__ user_neighbor, const int* __restrict__ item_neighbor,
    const int* __restrict__ adj_ent, const int* __restrict__ adj_rel,
    const float* __restrict__ usr_emb, const float* __restrict__ ent_emb,
    const float* __restrict__ rel_emb, const float* __restrict__ agg_W,
    const float* __restrict__ agg_b, float* __restrict__ out)
{
    const int wave = threadIdx.x >> 6;
    const int lane = threadIdx.x & 63;
    const int g = lane >> 4;   // group 0..3: owns neighbor rows 4g..4g+3
    const int s = lane & 15;   // chunk 0..15: dims [4s, 4s+4)
    const int b = __builtin_amdgcn_readfirstlane(blockIdx.x * WPB + wave);

    const f4* __restrict__ usr4 = (const f4*)usr_emb;
    const f4* __restrict__ ent4 = (const f4*)ent_emb;
    const f4* __restrict__ rel4 = (const f4*)rel_emb;
    const f4* __restrict__ W4   = (const f4*)agg_W;
    const f4* __restrict__ b4p  = (const f4*)agg_b;
    const int4* __restrict__ it4 = (const int4*)item_neighbor;
    const int4* __restrict__ un4 = (const int4*)user_neighbor;
    const int4* __restrict__ ar4 = (const int4*)adj_rel;
    const int4* __restrict__ ae4 = (const int4*)adj_ent;

    const int ub = __builtin_amdgcn_readfirstlane(u[b]);
    const int vb = __builtin_amdgcn_readfirstlane(v[b]);

    // ---- Per-lane contiguous index loads: one int4 per table (no scratch!).
    const int4 iit = it4[b * 4 + g];          // item_neighbor rows 4g..4g+3
    const int4 iun = un4[b * 4 + g];          // user_neighbor rows 4g..4g+3
    const int4 iar = ar4[vb * 4 + g];         // adj_rel rows 4g..4g+3
    const int4 iae = ae4[vb * 4 + g];         // adj_ent rows 4g..4g+3

    // ---- Direct rows.
    const f4 ue4 = usr4[(long)ub * 16 + s];
    const f4 ie4 = ent4[(long)vb * 16 + s];

    // ---- Row gathers: each instruction fetches 4 distinct rows (1 KB/wave).
    f4 Re[4], Ag[4], Lu[4], Li[4];
    Re[0] = rel4[iar.x * 16 + s];
    Re[1] = rel4[iar.y * 16 + s];
    Re[2] = rel4[iar.z * 16 + s];
    Re[3] = rel4[iar.w * 16 + s];
    Ag[0] = ent4[(long)iae.x * 16 + s];
    Ag[1] = ent4[(long)iae.y * 16 + s];
    Ag[2] = ent4[(long)iae.z * 16 + s];
    Ag[3] = ent4[(long)iae.w * 16 + s];
    Lu[0] = usr4[(long)iit.x * 16 + s];
    Lu[1] = usr4[(long)iit.y * 16 + s];
    Lu[2] = usr4[(long)iit.z * 16 + s];
    Lu[3] = usr4[(long)iit.w * 16 + s];
    Li[0] = ent4[(long)iun.x * 16 + s];
    Li[1] = ent4[(long)iun.y * 16 + s];
    Li[2] = ent4[(long)iun.z * 16 + s];
    Li[3] = ent4[(long)iun.w * 16 + s];

    // ---- Attention scores: sc[k] = dot(ue, rel_row[4g+k]) (in-group reduce).
    float sc[4];
#pragma unroll
    for (int k = 0; k < 4; k++) {
        float p = dot4(ue4, Re[k]);
        p += __shfl_xor(p, 1, 64); p += __shfl_xor(p, 2, 64);
        p += __shfl_xor(p, 4, 64); p += __shfl_xor(p, 8, 64);
        sc[k] = p;  // identical across the 16 lanes of group g
    }
    float m = fmaxf(fmaxf(sc[0], sc[1]), fmaxf(sc[2], sc[3]));
    m = fmaxf(m, __shfl_xor(m, 16, 64));
    m = fmaxf(m, __shfl_xor(m, 32, 64));
    float e[4];
    float ssum = 0.f;
#pragma unroll
    for (int k = 0; k < 4; k++) { e[k] = __expf(sc[k] - m); ssum += e[k]; }
    ssum += __shfl_xor(ssum, 16, 64);
    ssum += __shfl_xor(ssum, 32, 64);
    const float inv = 1.0f / ssum;

    // ---- neighbors_agg: this lane holds the attn weights for its own rows.
    f4 ag = {0.f, 0.f, 0.f, 0.f};
#pragma unroll
    for (int k = 0; k < 4; k++) {
        ag.x = fmaf(e[k], Ag[k].x, ag.x);
        ag.y = fmaf(e[k], Ag[k].y, ag.y);
        ag.z = fmaf(e[k], Ag[k].z, ag.z);
        ag.w = fmaf(e[k], Ag[k].w, ag.w);
    }
    ag = xgrp_sum(ag);  // sum over all 16 rows; replicated across groups

    f4 comb;
    comb.x = fmaf(ag.x, inv, ie4.x);
    comb.y = fmaf(ag.y, inv, ie4.y);
    comb.z = fmaf(ag.z, inv, ie4.z);
    comb.w = fmaf(ag.w, inv, ie4.w);
    const float cc[4] = {comb.x, comb.y, comb.z, comb.w};

    // ---- lite sums.
    f4 lu;
    lu.x = Lu[0].x + Lu[1].x + Lu[2].x + Lu[3].x;
    lu.y = Lu[0].y + Lu[1].y + Lu[2].y + Lu[3].y;
    lu.z = Lu[0].z + Lu[1].z + Lu[2].z + Lu[3].z;
    lu.w = Lu[0].w + Lu[1].w + Lu[2].w + Lu[3].w;
    lu = xgrp_sum(lu);
    f4 li;
    li.x = Li[0].x + Li[1].x + Li[2].x + Li[3].x;
    li.y = Li[0].y + Li[1].y + Li[2].y + Li[3].y;
    li.z = Li[0].z + Li[1].z + Li[2].z + Li[3].z;
    li.w = Li[0].w + Li[1].w + Li[2].w + Li[3].w;
    li = xgrp_sum(li);

    // ---- 64x64 matvec: lane (g,s) accumulates d in [16g,16g+16) for out-chunk s.
    // comb is replicated across groups; chunk 4g+(j>>2) lives in lane 20g+(j>>2).
    f4 acc = {0.f, 0.f, 0.f, 0.f};
#pragma unroll
    for (int j = 0; j < 16; j++) {
        const int d = 16 * g + j;
        const float cd = __shfl(cc[j & 3], 20 * g + (j >> 2), 64);
        const f4 w = W4[d * 16 + s];
        acc.x = fmaf(cd, w.x, acc.x);
        acc.y = fmaf(cd, w.y, acc.y);
        acc.z = fmaf(cd, w.z, acc.z);
        acc.w = fmaf(cd, w.w, acc.w);
    }
    acc = xgrp_sum(acc);
    const f4 bias = b4p[s];
    f4 item4;
    item4.x = tanhf(acc.x + bias.x);
    item4.y = tanhf(acc.y + bias.y);
    item4.z = tanhf(acc.z + bias.z);
    item4.w = tanhf(acc.w + bias.w);

    // ---- final score: dot over 64 dims = in-group reduce over 16 chunks.
    f4 uf, itf;
    uf.x = 0.5f * fmaf(lu.x, 1.f / NNB, ue4.x);
    uf.y = 0.5f * fmaf(lu.y, 1.f / NNB, ue4.y);
    uf.z = 0.5f * fmaf(lu.z, 1.f / NNB, ue4.z);
    uf.w = 0.5f * fmaf(lu.w, 1.f / NNB, ue4.w);
    itf.x = 0.5f * fmaf(li.x, 1.f / NNB, item4.x);
    itf.y = 0.5f * fmaf(li.y, 1.f / NNB, item4.y);
    itf.z = 0.5f * fmaf(li.z, 1.f / NNB, item4.z);
    itf.w = 0.5f * fmaf(li.w, 1.f / NNB, item4.w);

    float p = dot4(uf, itf);
    p += __shfl_xor(p, 1, 64); p += __shfl_xor(p, 2, 64);
    p += __shfl_xor(p, 4, 64); p += __shfl_xor(p, 8, 64);

    if (lane == 0) out[b] = 1.0f / (1.0f + __expf(-p));
}

extern "C" void kernel_launch(void* const* d_in, const int* in_sizes, int n_in,
                              void* d_out, int out_size, void* d_ws, size_t ws_size,
                              hipStream_t stream)
{
    const int*   u             = (const int*)d_in[0];
    const int*   v             = (const int*)d_in[1];
    const int*   user_neighbor = (const int*)d_in[2];
    const int*   item_neighbor = (const int*)d_in[3];
    const int*   adj_ent       = (const int*)d_in[4];
    const int*   adj_rel       = (const int*)d_in[5];
    const float* usr_emb       = (const float*)d_in[6];
    const float* ent_emb       = (const float*)d_in[7];
    const float* rel_emb       = (const float*)d_in[8];
    const float* agg_W         = (const float*)d_in[9];
    const float* agg_b         = (const float*)d_in[10];
    float* out = (float*)d_out;

    constexpr int WPB = 4;  // 4 waves/block, one batch element per wave
    dim3 grid(BATCH / WPB), block(WPB * 64);
    klgcn_kernel<WPB><<<grid, block, 0, stream>>>(
        u, v, user_neighbor, item_neighbor, adj_ent, adj_rel,
        usr_emb, ent_emb, rel_emb, agg_W, agg_b, out);
}

// Round 5
// 150.759 us; speedup vs baseline: 1.1816x; 1.0260x over previous
//
#include <hip/hip_runtime.h>
#include <math.h>

#define DIM 64
#define NNB 16
#define BATCH 16384

typedef float4 f4;

__device__ __forceinline__ float dot4(const f4 a, const f4 b) {
    return fmaf(a.x, b.x, fmaf(a.y, b.y, fmaf(a.z, b.z, a.w * b.w)));
}

// Sum across the 4 lane-groups (lanes differing in bits 4,5); chunk stays put.
__device__ __forceinline__ f4 xgrp_sum(f4 v) {
    v.x += __shfl_xor(v.x, 16, 64); v.y += __shfl_xor(v.y, 16, 64);
    v.z += __shfl_xor(v.z, 16, 64); v.w += __shfl_xor(v.w, 16, 64);
    v.x += __shfl_xor(v.x, 32, 64); v.y += __shfl_xor(v.y, 32, 64);
    v.z += __shfl_xor(v.z, 32, 64); v.w += __shfl_xor(v.w, 32, 64);
    return v;
}

// 2 batch elements per wave: ILP=2 on every latency chain, shared W reads.
template <int WPB>
__global__ __launch_bounds__(WPB * 64, 3) void klgcn_kernel(
    const int* __restrict__ u, const int* __restrict__ v,
    const int* __restrict__ user_neighbor, const int* __restrict__ item_neighbor,
    const int* __restrict__ adj_ent, const int* __restrict__ adj_rel,
    const float* __restrict__ usr_emb, const float* __restrict__ ent_emb,
    const float* __restrict__ rel_emb, const float* __restrict__ agg_W,
    const float* __restrict__ agg_b, float* __restrict__ out)
{
    const int wave = threadIdx.x >> 6;
    const int lane = threadIdx.x & 63;
    const int g = lane >> 4;   // group 0..3: owns neighbor rows 4g..4g+3
    const int s = lane & 15;   // chunk 0..15: dims [4s, 4s+4)
    const int b0 = __builtin_amdgcn_readfirstlane((blockIdx.x * WPB + wave) * 2);
    const int bb[2] = {b0, b0 + 1};

    const f4* __restrict__ usr4 = (const f4*)usr_emb;
    const f4* __restrict__ ent4 = (const f4*)ent_emb;
    const f4* __restrict__ rel4 = (const f4*)rel_emb;
    const f4* __restrict__ W4   = (const f4*)agg_W;
    const f4* __restrict__ b4p  = (const f4*)agg_b;
    const int4* __restrict__ it4 = (const int4*)item_neighbor;
    const int4* __restrict__ un4 = (const int4*)user_neighbor;
    const int4* __restrict__ ar4 = (const int4*)adj_rel;
    const int4* __restrict__ ae4 = (const int4*)adj_ent;

    // ---- Uniform scalars for both elements (s_load path).
    int ub[2], vb[2];
#pragma unroll
    for (int el = 0; el < 2; el++) {
        ub[el] = __builtin_amdgcn_readfirstlane(u[bb[el]]);
        vb[el] = __builtin_amdgcn_readfirstlane(v[bb[el]]);
    }

    // ---- Per-lane contiguous index loads: one int4 per table per element.
    int4 iit[2], iun[2], iar[2], iae[2];
#pragma unroll
    for (int el = 0; el < 2; el++) {
        iit[el] = it4[bb[el] * 4 + g];
        iun[el] = un4[bb[el] * 4 + g];
        iar[el] = ar4[vb[el] * 4 + g];
        iae[el] = ae4[vb[el] * 4 + g];
    }

    // ---- Direct rows.
    f4 ue4[2], ie4[2];
#pragma unroll
    for (int el = 0; el < 2; el++) {
        ue4[el] = usr4[(long)ub[el] * 16 + s];
        ie4[el] = ent4[(long)vb[el] * 16 + s];
    }

    // ---- Row gathers: each instr fetches 4 distinct rows (1 KB/wave).
    // Issue order = consumption order: Re (scores first), Ag, then lite rows.
    f4 Re[2][4], Ag[2][4], Lu[2][4], Li[2][4];
#pragma unroll
    for (int el = 0; el < 2; el++) {
        Re[el][0] = rel4[iar[el].x * 16 + s];
        Re[el][1] = rel4[iar[el].y * 16 + s];
        Re[el][2] = rel4[iar[el].z * 16 + s];
        Re[el][3] = rel4[iar[el].w * 16 + s];
    }
#pragma unroll
    for (int el = 0; el < 2; el++) {
        Ag[el][0] = ent4[(long)iae[el].x * 16 + s];
        Ag[el][1] = ent4[(long)iae[el].y * 16 + s];
        Ag[el][2] = ent4[(long)iae[el].z * 16 + s];
        Ag[el][3] = ent4[(long)iae[el].w * 16 + s];
    }
#pragma unroll
    for (int el = 0; el < 2; el++) {
        Lu[el][0] = usr4[(long)iit[el].x * 16 + s];
        Lu[el][1] = usr4[(long)iit[el].y * 16 + s];
        Lu[el][2] = usr4[(long)iit[el].z * 16 + s];
        Lu[el][3] = usr4[(long)iit[el].w * 16 + s];
    }
#pragma unroll
    for (int el = 0; el < 2; el++) {
        Li[el][0] = ent4[(long)iun[el].x * 16 + s];
        Li[el][1] = ent4[(long)iun[el].y * 16 + s];
        Li[el][2] = ent4[(long)iun[el].z * 16 + s];
        Li[el][3] = ent4[(long)iun[el].w * 16 + s];
    }

    // ---- Attention scores (two independent shuffle chains interleave).
    float e[2][4], inv[2];
#pragma unroll
    for (int el = 0; el < 2; el++) {
        float sc[4];
#pragma unroll
        for (int k = 0; k < 4; k++) {
            float p = dot4(ue4[el], Re[el][k]);
            p += __shfl_xor(p, 1, 64); p += __shfl_xor(p, 2, 64);
            p += __shfl_xor(p, 4, 64); p += __shfl_xor(p, 8, 64);
            sc[k] = p;
        }
        float m = fmaxf(fmaxf(sc[0], sc[1]), fmaxf(sc[2], sc[3]));
        m = fmaxf(m, __shfl_xor(m, 16, 64));
        m = fmaxf(m, __shfl_xor(m, 32, 64));
        float ssum = 0.f;
#pragma unroll
        for (int k = 0; k < 4; k++) { e[el][k] = __expf(sc[k] - m); ssum += e[el][k]; }
        ssum += __shfl_xor(ssum, 16, 64);
        ssum += __shfl_xor(ssum, 32, 64);
        inv[el] = 1.0f / ssum;
    }

    // ---- neighbors_agg + combined.
    float cc[2][4];
#pragma unroll
    for (int el = 0; el < 2; el++) {
        f4 ag = {0.f, 0.f, 0.f, 0.f};
#pragma unroll
        for (int k = 0; k < 4; k++) {
            ag.x = fmaf(e[el][k], Ag[el][k].x, ag.x);
            ag.y = fmaf(e[el][k], Ag[el][k].y, ag.y);
            ag.z = fmaf(e[el][k], Ag[el][k].z, ag.z);
            ag.w = fmaf(e[el][k], Ag[el][k].w, ag.w);
        }
        ag = xgrp_sum(ag);  // sum over all 16 rows; replicated across groups
        cc[el][0] = fmaf(ag.x, inv[el], ie4[el].x);
        cc[el][1] = fmaf(ag.y, inv[el], ie4[el].y);
        cc[el][2] = fmaf(ag.z, inv[el], ie4[el].z);
        cc[el][3] = fmaf(ag.w, inv[el], ie4[el].w);
    }

    // ---- lite sums.
    f4 lu[2], li[2];
#pragma unroll
    for (int el = 0; el < 2; el++) {
        f4 t;
        t.x = Lu[el][0].x + Lu[el][1].x + Lu[el][2].x + Lu[el][3].x;
        t.y = Lu[el][0].y + Lu[el][1].y + Lu[el][2].y + Lu[el][3].y;
        t.z = Lu[el][0].z + Lu[el][1].z + Lu[el][2].z + Lu[el][3].z;
        t.w = Lu[el][0].w + Lu[el][1].w + Lu[el][2].w + Lu[el][3].w;
        lu[el] = xgrp_sum(t);
        t.x = Li[el][0].x + Li[el][1].x + Li[el][2].x + Li[el][3].x;
        t.y = Li[el][0].y + Li[el][1].y + Li[el][2].y + Li[el][3].y;
        t.z = Li[el][0].z + Li[el][1].z + Li[el][2].z + Li[el][3].z;
        t.w = Li[el][0].w + Li[el][1].w + Li[el][2].w + Li[el][3].w;
        li[el] = xgrp_sum(t);
    }

    // ---- 64x64 matvec: one W load per j serves BOTH elements.
    // comb replicated across groups; chunk 4g+(j>>2) lives in lane 20g+(j>>2).
    f4 acc[2] = {{0.f, 0.f, 0.f, 0.f}, {0.f, 0.f, 0.f, 0.f}};
#pragma unroll
    for (int j = 0; j < 16; j++) {
        const int d = 16 * g + j;
        const f4 w = W4[d * 16 + s];
        const int src = 20 * g + (j >> 2);
#pragma unroll
        for (int el = 0; el < 2; el++) {
            const float cd = __shfl(cc[el][j & 3], src, 64);
            acc[el].x = fmaf(cd, w.x, acc[el].x);
            acc[el].y = fmaf(cd, w.y, acc[el].y);
            acc[el].z = fmaf(cd, w.z, acc[el].z);
            acc[el].w = fmaf(cd, w.w, acc[el].w);
        }
    }
    const f4 bias = b4p[s];
    float res[2];
#pragma unroll
    for (int el = 0; el < 2; el++) {
        acc[el] = xgrp_sum(acc[el]);
        f4 item4;
        item4.x = tanhf(acc[el].x + bias.x);
        item4.y = tanhf(acc[el].y + bias.y);
        item4.z = tanhf(acc[el].z + bias.z);
        item4.w = tanhf(acc[el].w + bias.w);

        f4 uf, itf;
        uf.x = 0.5f * fmaf(lu[el].x, 1.f / NNB, ue4[el].x);
        uf.y = 0.5f * fmaf(lu[el].y, 1.f / NNB, ue4[el].y);
        uf.z = 0.5f * fmaf(lu[el].z, 1.f / NNB, ue4[el].z);
        uf.w = 0.5f * fmaf(lu[el].w, 1.f / NNB, ue4[el].w);
        itf.x = 0.5f * fmaf(li[el].x, 1.f / NNB, item4.x);
        itf.y = 0.5f * fmaf(li[el].y, 1.f / NNB, item4.y);
        itf.z = 0.5f * fmaf(li[el].z, 1.f / NNB, item4.z);
        itf.w = 0.5f * fmaf(li[el].w, 1.f / NNB, item4.w);

        float p = dot4(uf, itf);
        p += __shfl_xor(p, 1, 64); p += __shfl_xor(p, 2, 64);
        p += __shfl_xor(p, 4, 64); p += __shfl_xor(p, 8, 64);
        res[el] = 1.0f / (1.0f + __expf(-p));
    }

    if (lane == 0) {
        // b0 is even -> 8B-aligned float2 store.
        *(float2*)(out + b0) = make_float2(res[0], res[1]);
    }
}

extern "C" void kernel_launch(void* const* d_in, const int* in_sizes, int n_in,
                              void* d_out, int out_size, void* d_ws, size_t ws_size,
                              hipStream_t stream)
{
    const int*   u             = (const int*)d_in[0];
    const int*   v             = (const int*)d_in[1];
    const int*   user_neighbor = (const int*)d_in[2];
    const int*   item_neighbor = (const int*)d_in[3];
    const int*   adj_ent       = (const int*)d_in[4];
    const int*   adj_rel       = (const int*)d_in[5];
    const float* usr_emb       = (const float*)d_in[6];
    const float* ent_emb       = (const float*)d_in[7];
    const float* rel_emb       = (const float*)d_in[8];
    const float* agg_W         = (const float*)d_in[9];
    const float* agg_b         = (const float*)d_in[10];
    float* out = (float*)d_out;

    constexpr int WPB = 4;  // 4 waves/block, TWO batch elements per wave
    dim3 grid(BATCH / (WPB * 2)), block(WPB * 64);
    klgcn_kernel<WPB><<<grid, block, 0, stream>>>(
        u, v, user_neighbor, item_neighbor, adj_ent, adj_rel,
        usr_emb, ent_emb, rel_emb, agg_W, agg_b, out);
}